// Round 1
// baseline (298.186 us; speedup 1.0000x reference)
//
#include <hip/hip_runtime.h>

typedef __bf16 bf16;
typedef __attribute__((ext_vector_type(8))) __bf16 bf16x8;
typedef __attribute__((ext_vector_type(4))) __bf16 bf16x4;
typedef __attribute__((ext_vector_type(4))) float floatx4;

#define MFMA16(a, b, c) __builtin_amdgcn_mfma_f32_16x16x32_bf16((a), (b), (c), 0, 0, 0)

static constexpr int BB = 2, SS = 2048, DD = 1024, HH = 16, HDIM = 64;
static constexpr int MM = BB * SS;      // 4096 rows
static constexpr int N_QKV = 3 * DD;    // 3072

// ---------------- fp32 -> bf16 cast of x ----------------
__global__ __launch_bounds__(256) void cvt_x_kernel(const float* __restrict__ x,
                                                    bf16* __restrict__ xb) {
    int i = (blockIdx.x * 256 + threadIdx.x) * 4;
    float4 v = *(const float4*)(x + i);
    bf16x4 o;
    o[0] = (bf16)v.x; o[1] = (bf16)v.y; o[2] = (bf16)v.z; o[3] = (bf16)v.w;
    *(bf16x4*)(xb + i) = o;
}

// ---------------- transpose + cast weights: W[K][N] -> WT[N][K] bf16 ----------------
// grid (32,32,4), block (32,8). z selects matrix; all 4 packed contiguously in outT.
__global__ __launch_bounds__(256) void cvt_wT_kernel(const float* __restrict__ w0,
                                                     const float* __restrict__ w1,
                                                     const float* __restrict__ w2,
                                                     const float* __restrict__ w3,
                                                     bf16* __restrict__ outT) {
    __shared__ float tile[32][33];
    const float* src = (blockIdx.z == 0) ? w0 : (blockIdx.z == 1) ? w1
                      : (blockIdx.z == 2) ? w2 : w3;
    bf16* dst = outT + (size_t)blockIdx.z * DD * DD;
    int x = blockIdx.x * 32 + threadIdx.x;   // n (src col)
    int y0 = blockIdx.y * 32;                // k (src row base)
    for (int i = threadIdx.y; i < 32; i += 8)
        tile[i][threadIdx.x] = src[(size_t)(y0 + i) * DD + x];
    __syncthreads();
    int xo = y0 + threadIdx.x;               // k (dst col)
    int yo0 = blockIdx.x * 32;               // n (dst row base)
    for (int i = threadIdx.y; i < 32; i += 8)
        dst[(size_t)(yo0 + i) * DD + xo] = (bf16)tile[threadIdx.x][i];
}

// ---------------- GEMM: C[M][N] = A[M][K] @ Bt[N][K]^T ----------------
// 64x64 tile / block, 256 threads = 4 waves in 2x2, each wave 32x32 (2x2 mfma tiles).
// Cb != null -> bf16 out; else Cf fp32 out (+bias if non-null).
__global__ __launch_bounds__(256) void gemm_kernel(const bf16* __restrict__ A,
                                                   const bf16* __restrict__ Bt,
                                                   bf16* __restrict__ Cb,
                                                   float* __restrict__ Cf,
                                                   const float* __restrict__ bias,
                                                   int K, int ldc) {
    __shared__ bf16 As[64][72];
    __shared__ bf16 Bs[64][72];
    int tid = threadIdx.x;
    int wave = tid >> 6, lane = tid & 63;
    int quad = lane >> 4, l16 = lane & 15;
    int wm = wave >> 1, wn = wave & 1;
    int m0 = blockIdx.y * 64, n0 = blockIdx.x * 64;
    int srow = tid >> 2, sseg = tid & 3;

    floatx4 acc[2][2] = {};
    const uint4* pa = (const uint4*)(A + (size_t)(m0 + srow) * K + sseg * 16);
    const uint4* pb = (const uint4*)(Bt + (size_t)(n0 + srow) * K + sseg * 16);

    for (int k0 = 0; k0 < K; k0 += 64) {
        uint4 a0 = pa[0], a1 = pa[1];
        uint4 b0 = pb[0], b1 = pb[1];
        pa += 8; pb += 8;  // advance 64 bf16
        uint4* da = (uint4*)&As[srow][sseg * 16];
        da[0] = a0; da[1] = a1;
        uint4* db = (uint4*)&Bs[srow][sseg * 16];
        db[0] = b0; db[1] = b1;
        __syncthreads();
#pragma unroll
        for (int c = 0; c < 2; ++c) {
            bf16x8 af0 = *(const bf16x8*)&As[wm * 32 + l16][c * 32 + quad * 8];
            bf16x8 af1 = *(const bf16x8*)&As[wm * 32 + 16 + l16][c * 32 + quad * 8];
            bf16x8 bf0 = *(const bf16x8*)&Bs[wn * 32 + l16][c * 32 + quad * 8];
            bf16x8 bf1 = *(const bf16x8*)&Bs[wn * 32 + 16 + l16][c * 32 + quad * 8];
            acc[0][0] = MFMA16(af0, bf0, acc[0][0]);
            acc[0][1] = MFMA16(af0, bf1, acc[0][1]);
            acc[1][0] = MFMA16(af1, bf0, acc[1][0]);
            acc[1][1] = MFMA16(af1, bf1, acc[1][1]);
        }
        __syncthreads();
    }

#pragma unroll
    for (int i = 0; i < 2; ++i)
#pragma unroll
        for (int j = 0; j < 2; ++j)
#pragma unroll
            for (int r = 0; r < 4; ++r) {
                int row = m0 + wm * 32 + i * 16 + quad * 4 + r;
                int col = n0 + wn * 32 + j * 16 + l16;
                float v = acc[i][j][r];
                if (Cf) Cf[(size_t)row * ldc + col] = v + (bias ? bias[col] : 0.f);
                else    Cb[(size_t)row * ldc + col] = (bf16)v;
            }
}

// ---------------- fused causal attention (flash-style) ----------------
// grid (qt=32, bh=32), block 256 (4 waves); wave w handles q rows [q0+16w, q0+16w+16).
// QKV layout: [4096][3072], Q at col h*64, K at 1024+h*64, V at 2048+h*64.
__global__ __launch_bounds__(256) void attn_kernel(const bf16* __restrict__ QKV,
                                                   bf16* __restrict__ ctx) {
    __shared__ bf16 Qs[64][72];
    __shared__ bf16 Ks[64][72];
    __shared__ bf16 Vt[64][72];      // Vt[n=hd][k=key]
    __shared__ bf16 Ps[4][16][72];   // per-wave P tile (C-layout -> A-layout round trip)

    int tid = threadIdx.x;
    int wave = tid >> 6, lane = tid & 63;
    int quad = lane >> 4, l16 = lane & 15;
    int qt = blockIdx.x, bh = blockIdx.y;
    int b = bh >> 4, h = bh & 15;
    int q0 = qt * 64;
    int srow = tid >> 2, sseg = tid & 3;
    const size_t base = (size_t)(b * SS) * N_QKV;

    {   // Q tile once
        const uint4* pq = (const uint4*)(QKV + base + (size_t)(q0 + srow) * N_QKV + h * 64 + sseg * 16);
        uint4 q0v = pq[0], q1v = pq[1];
        uint4* dq = (uint4*)&Qs[srow][sseg * 16];
        dq[0] = q0v; dq[1] = q1v;
    }

    floatx4 accv[4] = {};
    floatx4 m_run = { -__builtin_inff(), -__builtin_inff(), -__builtin_inff(), -__builtin_inff() };
    floatx4 l_run = {};

    for (int kt = 0; kt <= qt; ++kt) {
        int k0 = kt * 64;
        {   // stage K rows + V transposed
            const bf16* krow = QKV + base + (size_t)(k0 + srow) * N_QKV + 1024 + h * 64 + sseg * 16;
            const bf16* vrow = QKV + base + (size_t)(k0 + srow) * N_QKV + 2048 + h * 64 + sseg * 16;
            uint4 k0v = ((const uint4*)krow)[0], k1v = ((const uint4*)krow)[1];
            bf16x8 v0 = *(const bf16x8*)vrow;
            bf16x8 v1 = *(const bf16x8*)(vrow + 8);
            uint4* dk = (uint4*)&Ks[srow][sseg * 16];
            dk[0] = k0v; dk[1] = k1v;
#pragma unroll
            for (int e = 0; e < 8; ++e) Vt[sseg * 16 + e][srow] = v0[e];
#pragma unroll
            for (int e = 0; e < 8; ++e) Vt[sseg * 16 + 8 + e][srow] = v1[e];
        }
        __syncthreads();

        // scores: S = Q(16x64) @ K^T -> 4 col-tiles
        floatx4 s[4];
#pragma unroll
        for (int j = 0; j < 4; ++j) {
            s[j] = (floatx4){0.f, 0.f, 0.f, 0.f};
#pragma unroll
            for (int c = 0; c < 2; ++c) {
                bf16x8 af  = *(const bf16x8*)&Qs[wave * 16 + l16][c * 32 + quad * 8];
                bf16x8 bfr = *(const bf16x8*)&Ks[j * 16 + l16][c * 32 + quad * 8];
                s[j] = MFMA16(af, bfr, s[j]);
            }
        }

        // causal mask + scale (mask -> -inf before scale, matches reference)
        int qrow = q0 + wave * 16 + quad * 4;
#pragma unroll
        for (int j = 0; j < 4; ++j) {
            int kc = k0 + j * 16 + l16;
#pragma unroll
            for (int r = 0; r < 4; ++r)
                s[j][r] = (kc > qrow + r) ? -__builtin_inff() : s[j][r] * 0.125f;
        }

        // online softmax (rows live across 16 lanes: shuffle-xor 1,2,4,8)
        floatx4 mloc = s[0];
#pragma unroll
        for (int j = 1; j < 4; ++j)
#pragma unroll
            for (int r = 0; r < 4; ++r) mloc[r] = fmaxf(mloc[r], s[j][r]);
#pragma unroll
        for (int off = 1; off < 16; off <<= 1)
#pragma unroll
            for (int r = 0; r < 4; ++r) mloc[r] = fmaxf(mloc[r], __shfl_xor(mloc[r], off, 64));

        floatx4 m_new, alpha;
#pragma unroll
        for (int r = 0; r < 4; ++r) {
            m_new[r] = fmaxf(m_run[r], mloc[r]);
            alpha[r] = __expf(m_run[r] - m_new[r]);
        }

        floatx4 lsum = {};
#pragma unroll
        for (int j = 0; j < 4; ++j)
#pragma unroll
            for (int r = 0; r < 4; ++r) {
                s[j][r] = __expf(s[j][r] - m_new[r]);
                lsum[r] += s[j][r];
            }
#pragma unroll
        for (int off = 1; off < 16; off <<= 1)
#pragma unroll
            for (int r = 0; r < 4; ++r) lsum[r] += __shfl_xor(lsum[r], off, 64);

#pragma unroll
        for (int r = 0; r < 4; ++r) l_run[r] = l_run[r] * alpha[r] + lsum[r];
#pragma unroll
        for (int j = 0; j < 4; ++j)
#pragma unroll
            for (int r = 0; r < 4; ++r) accv[j][r] *= alpha[r];
        m_run = m_new;

        // P: C-layout -> LDS -> A-layout
#pragma unroll
        for (int j = 0; j < 4; ++j)
#pragma unroll
            for (int r = 0; r < 4; ++r)
                Ps[wave][quad * 4 + r][j * 16 + l16] = (bf16)s[j][r];
        __syncthreads();

        // ctx += P(16x64) @ V(64x64)
#pragma unroll
        for (int j = 0; j < 4; ++j)
#pragma unroll
            for (int c = 0; c < 2; ++c) {
                bf16x8 af  = *(const bf16x8*)&Ps[wave][l16][c * 32 + quad * 8];
                bf16x8 bfr = *(const bf16x8*)&Vt[j * 16 + l16][c * 32 + quad * 8];
                accv[j] = MFMA16(af, bfr, accv[j]);
            }
        __syncthreads();
    }

    // epilogue: ctx [4096][1024] bf16
#pragma unroll
    for (int j = 0; j < 4; ++j)
#pragma unroll
        for (int r = 0; r < 4; ++r) {
            int row = b * SS + q0 + wave * 16 + quad * 4 + r;
            int col = h * 64 + j * 16 + l16;
            ctx[(size_t)row * DD + col] = (bf16)(accv[j][r] / l_run[r]);
        }
}

extern "C" void kernel_launch(void* const* d_in, const int* in_sizes, int n_in,
                              void* d_out, int out_size, void* d_ws, size_t ws_size,
                              hipStream_t stream) {
    const float* x  = (const float*)d_in[0];
    const float* Wq = (const float*)d_in[1];
    const float* Wk = (const float*)d_in[2];
    const float* Wv = (const float*)d_in[3];
    const float* Wo = (const float*)d_in[4];
    const float* bo = (const float*)d_in[5];
    float* out = (float*)d_out;

    char* ws = (char*)d_ws;
    bf16* xb   = (bf16*)ws;                         // 4096*1024*2  =  8 MB
    bf16* WT   = (bf16*)(ws + (size_t)(8  << 20));  // 4*1024*1024*2 = 8 MB (Wq,Wk,Wv,Wo transposed)
    bf16* QKV  = (bf16*)(ws + (size_t)(16 << 20));  // 4096*3072*2  = 24 MB
    bf16* ctxb = (bf16*)(ws + (size_t)(40 << 20));  // 4096*1024*2  =  8 MB

    cvt_x_kernel<<<dim3(MM * DD / (256 * 4)), dim3(256), 0, stream>>>(x, xb);
    cvt_wT_kernel<<<dim3(32, 32, 4), dim3(32, 8), 0, stream>>>(Wq, Wk, Wv, Wo, WT);
    // QKV: [4096,1024] x [1024,3072] -> [4096,3072] bf16
    gemm_kernel<<<dim3(N_QKV / 64, MM / 64), dim3(256), 0, stream>>>(
        xb, WT, QKV, nullptr, nullptr, DD, N_QKV);
    // attention -> ctx [4096,1024] bf16
    attn_kernel<<<dim3(SS / 64, BB * HH), dim3(256), 0, stream>>>(QKV, ctxb);
    // out-proj: [4096,1024] x [1024,1024] + bias -> fp32 d_out
    gemm_kernel<<<dim3(DD / 64, MM / 64), dim3(256), 0, stream>>>(
        ctxb, WT + (size_t)3 * DD * DD, nullptr, out, bo, DD, DD);
}

// Round 2
// 218.483 us; speedup vs baseline: 1.3648x; 1.3648x over previous
//
#include <hip/hip_runtime.h>

typedef __bf16 bf16;
typedef __attribute__((ext_vector_type(8))) __bf16 bf16x8;
typedef __attribute__((ext_vector_type(4))) __bf16 bf16x4;
typedef __attribute__((ext_vector_type(4))) float floatx4;

#define MFMA16(a, b, c) __builtin_amdgcn_mfma_f32_16x16x32_bf16((a), (b), (c), 0, 0, 0)

static constexpr int BB = 2, SS = 2048, DD = 1024, HH = 16;
static constexpr int MM = BB * SS;      // 4096
static constexpr int N_QKV = 3 * DD;    // 3072

// async 16B global->LDS (lane i of wave lands at ldsbase + i*16)
__device__ __forceinline__ void async16(const void* g, void* l) {
    __builtin_amdgcn_global_load_lds(
        (const __attribute__((address_space(1))) unsigned int*)g,
        (__attribute__((address_space(3))) unsigned int*)l, 16, 0, 0);
}

// ---------------- fp32 -> bf16 cast of x ----------------
__global__ __launch_bounds__(256) void cvt_x_kernel(const float* __restrict__ x,
                                                    bf16* __restrict__ xb) {
    int i = (blockIdx.x * 256 + threadIdx.x) * 4;
    float4 v = *(const float4*)(x + i);
    bf16x4 o;
    o[0] = (bf16)v.x; o[1] = (bf16)v.y; o[2] = (bf16)v.z; o[3] = (bf16)v.w;
    *(bf16x4*)(xb + i) = o;
}

// ---------------- transpose + cast weights: W[K][N] -> WT[N][K] bf16 ----------------
__global__ __launch_bounds__(256) void cvt_wT_kernel(const float* __restrict__ w0,
                                                     const float* __restrict__ w1,
                                                     const float* __restrict__ w2,
                                                     const float* __restrict__ w3,
                                                     bf16* __restrict__ outT) {
    __shared__ float tile[32][33];
    const float* src = (blockIdx.z == 0) ? w0 : (blockIdx.z == 1) ? w1
                      : (blockIdx.z == 2) ? w2 : w3;
    bf16* dst = outT + (size_t)blockIdx.z * DD * DD;
    int x = blockIdx.x * 32 + threadIdx.x;
    int y0 = blockIdx.y * 32;
    for (int i = threadIdx.y; i < 32; i += 8)
        tile[i][threadIdx.x] = src[(size_t)(y0 + i) * DD + x];
    __syncthreads();
    int xo = y0 + threadIdx.x;
    int yo0 = blockIdx.x * 32;
    for (int i = threadIdx.y; i < 32; i += 8)
        dst[(size_t)(yo0 + i) * DD + xo] = (bf16)tile[threadIdx.x][i];
}

// ---------------- V transpose: QKV V-part [b,s][h,hd] -> Vt_g[bh][hd][s] ----------------
__global__ __launch_bounds__(256) void transpose_v_kernel(const bf16* __restrict__ QKV,
                                                          bf16* __restrict__ Vt_g) {
    __shared__ bf16 t[64][72];
    const int tid = threadIdx.x, srow = tid >> 2, sseg = tid & 3;
    const int bh = blockIdx.y, b = bh >> 4, h = bh & 15;
    const int s0 = blockIdx.x * 64;
    {
        const uint4* p = (const uint4*)(QKV + (size_t)(b * SS + s0 + srow) * N_QKV
                                        + 2 * DD + h * 64 + sseg * 16);
        uint4 a = p[0], c = p[1];
        uint4* d = (uint4*)&t[srow][sseg * 16];
        d[0] = a; d[1] = c;
    }
    __syncthreads();
    bf16x8 o0, o1;
#pragma unroll
    for (int e = 0; e < 8; ++e) o0[e] = t[sseg * 16 + e][srow];
#pragma unroll
    for (int e = 0; e < 8; ++e) o1[e] = t[sseg * 16 + 8 + e][srow];
    uint4* d = (uint4*)(Vt_g + ((size_t)bh * 64 + srow) * SS + s0 + sseg * 16);
    d[0] = *(uint4*)&o0; d[1] = *(uint4*)&o1;
}

// ---------------- GEMM (m97-style): C[M][N] = A[M][K] @ Bt[N][K]^T ----------------
// BMxBN tile, BK=64, 256 threads = 4 waves (2x2), global_load_lds staging with XOR swizzle:
// LDS chunk c of row r holds global chunk c^(r&7)  (chunk = 8 bf16 = 16B).
template <int BM, int BN, bool OUT_BF16>
__global__ __launch_bounds__(256) void gemm_kernel(const bf16* __restrict__ A,
                                                   const bf16* __restrict__ Bt,
                                                   void* __restrict__ C,
                                                   const float* __restrict__ bias,
                                                   int K, int ldc) {
    constexpr int MT = BM / 32, NT = BN / 32;
    __shared__ bf16 As[BM * 64];
    __shared__ bf16 Bs[BN * 64];
    const int tid = threadIdx.x, wave = tid >> 6, lane = tid & 63;
    const int quad = lane >> 4, l16 = lane & 15;
    const int wm = wave >> 1, wn = wave & 1;
    const int m0 = blockIdx.y * BM, n0 = blockIdx.x * BN;
    const int l8r = lane >> 3, l8c = lane & 7;
    const int gch = ((l8c ^ l8r) * 8);   // element offset of swizzled global chunk

    floatx4 acc[MT][NT] = {};

    for (int k0 = 0; k0 < K; k0 += 64) {
        __syncthreads();   // previous iteration's readers done
#pragma unroll
        for (int c = 0; c < BM / 32; ++c) {
            int r = wave * (BM / 4) + c * 8;
            async16(A + (size_t)(m0 + r + l8r) * K + k0 + gch, &As[r * 64]);
        }
#pragma unroll
        for (int c = 0; c < BN / 32; ++c) {
            int r = wave * (BN / 4) + c * 8;
            async16(Bt + (size_t)(n0 + r + l8r) * K + k0 + gch, &Bs[r * 64]);
        }
        __syncthreads();   // staging complete (vmcnt drained before barrier)
#pragma unroll
        for (int cc = 0; cc < 2; ++cc) {
            bf16x8 af[MT], bv[NT];
#pragma unroll
            for (int i = 0; i < MT; ++i) {
                int row = wm * (BM / 2) + i * 16 + l16;
                af[i] = *(const bf16x8*)&As[row * 64 + ((cc * 4 + quad) ^ (row & 7)) * 8];
            }
#pragma unroll
            for (int j = 0; j < NT; ++j) {
                int row = wn * (BN / 2) + j * 16 + l16;
                bv[j] = *(const bf16x8*)&Bs[row * 64 + ((cc * 4 + quad) ^ (row & 7)) * 8];
            }
#pragma unroll
            for (int i = 0; i < MT; ++i)
#pragma unroll
                for (int j = 0; j < NT; ++j)
                    acc[i][j] = MFMA16(af[i], bv[j], acc[i][j]);
        }
    }

#pragma unroll
    for (int i = 0; i < MT; ++i)
#pragma unroll
        for (int j = 0; j < NT; ++j)
#pragma unroll
            for (int r = 0; r < 4; ++r) {
                int row = m0 + wm * (BM / 2) + i * 16 + quad * 4 + r;
                int col = n0 + wn * (BN / 2) + j * 16 + l16;
                if (OUT_BF16)
                    ((bf16*)C)[(size_t)row * ldc + col] = (bf16)acc[i][j][r];
                else
                    ((float*)C)[(size_t)row * ldc + col] = acc[i][j][r] + bias[col];
            }
}

// ---------------- fused causal attention (flash-style) ----------------
// grid (16 qpairs, 32 bh). Block handles q-tiles qp and 31-qp (constant 33 k-iterations).
// Register double-buffer for K/V staging; V pre-transposed in Vt_g.
__global__ __launch_bounds__(256) void attn_kernel(const bf16* __restrict__ QKV,
                                                   const bf16* __restrict__ Vt_g,
                                                   bf16* __restrict__ ctx) {
    __shared__ bf16 Qs[64][72];
    __shared__ bf16 Ks[64][72];
    __shared__ bf16 Vt[64][72];      // [hd][key]
    __shared__ bf16 Ps[4][16][72];   // per-wave P tile

    const int tid = threadIdx.x, wave = tid >> 6, lane = tid & 63;
    const int quad = lane >> 4, l16 = lane & 15;
    const int qp = blockIdx.x, bh = blockIdx.y, b = bh >> 4, h = bh & 15;
    const int srow = tid >> 2, sseg = tid & 3;
    const size_t base = (size_t)(b * SS) * N_QKV;
    const bf16* Vg = Vt_g + (size_t)bh * 64 * SS;

    for (int half = 0; half < 2; ++half) {
        const int qt = half ? (31 - qp) : qp;
        const int q0 = qt * 64;

        {   // stage Q (visible after first in-loop barrier)
            const uint4* pq = (const uint4*)(QKV + base + (size_t)(q0 + srow) * N_QKV
                                             + h * 64 + sseg * 16);
            uint4 a = pq[0], bq = pq[1];
            uint4* d = (uint4*)&Qs[srow][sseg * 16];
            d[0] = a; d[1] = bq;
        }
        // prefetch kv tile 0 into registers
        uint4 kr0, kr1, vr0, vr1;
        {
            const uint4* pk = (const uint4*)(QKV + base + (size_t)srow * N_QKV
                                             + DD + h * 64 + sseg * 16);
            kr0 = pk[0]; kr1 = pk[1];
            const uint4* pv = (const uint4*)(Vg + (size_t)srow * SS + sseg * 16);
            vr0 = pv[0]; vr1 = pv[1];
        }

        floatx4 accv[4] = {};
        floatx4 m_run = { -__builtin_inff(), -__builtin_inff(), -__builtin_inff(), -__builtin_inff() };
        floatx4 l_run = {};

        for (int kt = 0; kt <= qt; ++kt) {
            {   // commit prefetched tile to LDS
                uint4* dk = (uint4*)&Ks[srow][sseg * 16];
                dk[0] = kr0; dk[1] = kr1;
                uint4* dv = (uint4*)&Vt[srow][sseg * 16];
                dv[0] = vr0; dv[1] = vr1;
            }
            __syncthreads();
            if (kt < qt) {   // prefetch next tile (hidden under compute)
                int k0n = (kt + 1) * 64;
                const uint4* pk = (const uint4*)(QKV + base + (size_t)(k0n + srow) * N_QKV
                                                 + DD + h * 64 + sseg * 16);
                kr0 = pk[0]; kr1 = pk[1];
                const uint4* pv = (const uint4*)(Vg + (size_t)srow * SS + k0n + sseg * 16);
                vr0 = pv[0]; vr1 = pv[1];
            }
            const int k0 = kt * 64;

            // S = Q(16x64) @ K^T
            bf16x8 qf0 = *(const bf16x8*)&Qs[wave * 16 + l16][quad * 8];
            bf16x8 qf1 = *(const bf16x8*)&Qs[wave * 16 + l16][32 + quad * 8];
            floatx4 s[4];
#pragma unroll
            for (int j = 0; j < 4; ++j) {
                bf16x8 kf0 = *(const bf16x8*)&Ks[j * 16 + l16][quad * 8];
                bf16x8 kf1 = *(const bf16x8*)&Ks[j * 16 + l16][32 + quad * 8];
                floatx4 t = {};
                t = MFMA16(qf0, kf0, t);
                t = MFMA16(qf1, kf1, t);
                s[j] = t;
            }

            // causal mask + scale
            int qrow = q0 + wave * 16 + quad * 4;
#pragma unroll
            for (int j = 0; j < 4; ++j) {
                int kc = k0 + j * 16 + l16;
#pragma unroll
                for (int r = 0; r < 4; ++r)
                    s[j][r] = (kc > qrow + r) ? -__builtin_inff() : s[j][r] * 0.125f;
            }

            // online softmax (rows spread over 16 lanes)
            floatx4 mloc = s[0];
#pragma unroll
            for (int j = 1; j < 4; ++j)
#pragma unroll
                for (int r = 0; r < 4; ++r) mloc[r] = fmaxf(mloc[r], s[j][r]);
#pragma unroll
            for (int off = 1; off < 16; off <<= 1)
#pragma unroll
                for (int r = 0; r < 4; ++r) mloc[r] = fmaxf(mloc[r], __shfl_xor(mloc[r], off, 64));

            floatx4 m_new, alpha;
#pragma unroll
            for (int r = 0; r < 4; ++r) {
                m_new[r] = fmaxf(m_run[r], mloc[r]);
                alpha[r] = __expf(m_run[r] - m_new[r]);
            }

            floatx4 lsum = {};
#pragma unroll
            for (int j = 0; j < 4; ++j)
#pragma unroll
                for (int r = 0; r < 4; ++r) {
                    s[j][r] = __expf(s[j][r] - m_new[r]);
                    lsum[r] += s[j][r];
                }
#pragma unroll
            for (int off = 1; off < 16; off <<= 1)
#pragma unroll
                for (int r = 0; r < 4; ++r) lsum[r] += __shfl_xor(lsum[r], off, 64);

#pragma unroll
            for (int r = 0; r < 4; ++r) l_run[r] = l_run[r] * alpha[r] + lsum[r];
#pragma unroll
            for (int j = 0; j < 4; ++j)
#pragma unroll
                for (int r = 0; r < 4; ++r) accv[j][r] *= alpha[r];
            m_run = m_new;

            // P: C-layout -> LDS (per-wave private; wave-lockstep LDS, no barrier)
#pragma unroll
            for (int j = 0; j < 4; ++j)
#pragma unroll
                for (int r = 0; r < 4; ++r)
                    Ps[wave][quad * 4 + r][j * 16 + l16] = (bf16)s[j][r];

            // ctx += P(16x64) @ V
            bf16x8 pf0 = *(const bf16x8*)&Ps[wave][l16][quad * 8];
            bf16x8 pf1 = *(const bf16x8*)&Ps[wave][l16][32 + quad * 8];
#pragma unroll
            for (int j = 0; j < 4; ++j) {
                bf16x8 vt0 = *(const bf16x8*)&Vt[j * 16 + l16][quad * 8];
                bf16x8 vt1 = *(const bf16x8*)&Vt[j * 16 + l16][32 + quad * 8];
                accv[j] = MFMA16(pf0, vt0, accv[j]);
                accv[j] = MFMA16(pf1, vt1, accv[j]);
            }
            __syncthreads();
        }

        // epilogue
#pragma unroll
        for (int j = 0; j < 4; ++j)
#pragma unroll
            for (int r = 0; r < 4; ++r) {
                int row = b * SS + q0 + wave * 16 + quad * 4 + r;
                int col = h * 64 + j * 16 + l16;
                ctx[(size_t)row * DD + col] = (bf16)(accv[j][r] / l_run[r]);
            }
    }
}

extern "C" void kernel_launch(void* const* d_in, const int* in_sizes, int n_in,
                              void* d_out, int out_size, void* d_ws, size_t ws_size,
                              hipStream_t stream) {
    const float* x  = (const float*)d_in[0];
    const float* Wq = (const float*)d_in[1];
    const float* Wk = (const float*)d_in[2];
    const float* Wv = (const float*)d_in[3];
    const float* Wo = (const float*)d_in[4];
    const float* bo = (const float*)d_in[5];
    float* out = (float*)d_out;

    char* ws = (char*)d_ws;
    bf16* xb   = (bf16*)ws;                         //  8 MB
    bf16* WT   = (bf16*)(ws + (size_t)(8  << 20));  //  8 MB
    bf16* QKV  = (bf16*)(ws + (size_t)(16 << 20));  // 24 MB
    bf16* ctxb = (bf16*)(ws + (size_t)(40 << 20));  //  8 MB
    bf16* Vt_g = (bf16*)(ws + (size_t)(48 << 20));  //  8 MB

    cvt_x_kernel<<<dim3(MM * DD / (256 * 4)), dim3(256), 0, stream>>>(x, xb);
    cvt_wT_kernel<<<dim3(32, 32, 4), dim3(32, 8), 0, stream>>>(Wq, Wk, Wv, Wo, WT);
    gemm_kernel<128, 128, true><<<dim3(N_QKV / 128, MM / 128), dim3(256), 0, stream>>>(
        xb, WT, QKV, nullptr, DD, N_QKV);
    transpose_v_kernel<<<dim3(SS / 64, BB * HH), dim3(256), 0, stream>>>(QKV, Vt_g);
    attn_kernel<<<dim3(16, BB * HH), dim3(256), 0, stream>>>(QKV, Vt_g, ctxb);
    gemm_kernel<128, 64, false><<<dim3(DD / 64, MM / 128), dim3(256), 0, stream>>>(
        ctxb, WT + (size_t)3 * DD * DD, out, bo, DD, DD);
}

// Round 3
// 189.350 us; speedup vs baseline: 1.5748x; 1.1539x over previous
//
#include <hip/hip_runtime.h>

typedef __bf16 bf16;
typedef __attribute__((ext_vector_type(8))) __bf16 bf16x8;
typedef __attribute__((ext_vector_type(4))) __bf16 bf16x4;
typedef __attribute__((ext_vector_type(4))) float floatx4;

#define MFMA16(a, b, c) __builtin_amdgcn_mfma_f32_16x16x32_bf16((a), (b), (c), 0, 0, 0)

static constexpr int BB = 2, SS = 2048, DD = 1024, HH = 16;
static constexpr int MM = BB * SS;      // 4096
static constexpr int N_QKV = 3 * DD;    // 3072

__device__ __forceinline__ float exp2c(float x) {
#if __has_builtin(__builtin_amdgcn_exp2f)
    return __builtin_amdgcn_exp2f(x);
#else
    return exp2f(x);
#endif
}

// async 16B global->LDS (lane i of wave lands at ldsbase + i*16)
__device__ __forceinline__ void async16(const void* g, void* l) {
    __builtin_amdgcn_global_load_lds(
        (const __attribute__((address_space(1))) unsigned int*)g,
        (__attribute__((address_space(3))) unsigned int*)l, 16, 0, 0);
}

// ---------------- fp32 -> bf16 cast of x ----------------
__global__ __launch_bounds__(256) void cvt_x_kernel(const float* __restrict__ x,
                                                    bf16* __restrict__ xb) {
    int i = (blockIdx.x * 256 + threadIdx.x) * 4;
    float4 v = *(const float4*)(x + i);
    bf16x4 o;
    o[0] = (bf16)v.x; o[1] = (bf16)v.y; o[2] = (bf16)v.z; o[3] = (bf16)v.w;
    *(bf16x4*)(xb + i) = o;
}

// ---------------- transpose + cast weights: W[K][N] -> WT[N][K] bf16 ----------------
__global__ __launch_bounds__(256) void cvt_wT_kernel(const float* __restrict__ w0,
                                                     const float* __restrict__ w1,
                                                     const float* __restrict__ w2,
                                                     const float* __restrict__ w3,
                                                     bf16* __restrict__ outT) {
    __shared__ float tile[32][33];
    const float* src = (blockIdx.z == 0) ? w0 : (blockIdx.z == 1) ? w1
                      : (blockIdx.z == 2) ? w2 : w3;
    bf16* dst = outT + (size_t)blockIdx.z * DD * DD;
    int x = blockIdx.x * 32 + threadIdx.x;
    int y0 = blockIdx.y * 32;
    for (int i = threadIdx.y; i < 32; i += 8)
        tile[i][threadIdx.x] = src[(size_t)(y0 + i) * DD + x];
    __syncthreads();
    int xo = y0 + threadIdx.x;
    int yo0 = blockIdx.x * 32;
    for (int i = threadIdx.y; i < 32; i += 8)
        dst[(size_t)(yo0 + i) * DD + xo] = (bf16)tile[threadIdx.x][i];
}

// ---------------- V transpose: QKV V-part [b,s][h,hd] -> Vt_g[bh][hd][s] ----------------
__global__ __launch_bounds__(256) void transpose_v_kernel(const bf16* __restrict__ QKV,
                                                          bf16* __restrict__ Vt_g) {
    __shared__ bf16 t[64][72];
    const int tid = threadIdx.x, srow = tid >> 2, sseg = tid & 3;
    const int bh = blockIdx.y, b = bh >> 4, h = bh & 15;
    const int s0 = blockIdx.x * 64;
    {
        const uint4* p = (const uint4*)(QKV + (size_t)(b * SS + s0 + srow) * N_QKV
                                        + 2 * DD + h * 64 + sseg * 16);
        uint4 a = p[0], c = p[1];
        uint4* d = (uint4*)&t[srow][sseg * 16];
        d[0] = a; d[1] = c;
    }
    __syncthreads();
    bf16x8 o0, o1;
#pragma unroll
    for (int e = 0; e < 8; ++e) o0[e] = t[sseg * 16 + e][srow];
#pragma unroll
    for (int e = 0; e < 8; ++e) o1[e] = t[sseg * 16 + 8 + e][srow];
    uint4* d = (uint4*)(Vt_g + ((size_t)bh * 64 + srow) * SS + s0 + sseg * 16);
    d[0] = *(uint4*)&o0; d[1] = *(uint4*)&o1;
}

// ---------------- GEMM (m97-style): C[M][N] = A[M][K] @ Bt[N][K]^T ----------------
template <int BM, int BN, bool OUT_BF16>
__global__ __launch_bounds__(256) void gemm_kernel(const bf16* __restrict__ A,
                                                   const bf16* __restrict__ Bt,
                                                   void* __restrict__ C,
                                                   const float* __restrict__ bias,
                                                   int K, int ldc) {
    constexpr int MT = BM / 32, NT = BN / 32;
    __shared__ bf16 As[BM * 64];
    __shared__ bf16 Bs[BN * 64];
    const int tid = threadIdx.x, wave = tid >> 6, lane = tid & 63;
    const int quad = lane >> 4, l16 = lane & 15;
    const int wm = wave >> 1, wn = wave & 1;
    const int m0 = blockIdx.y * BM, n0 = blockIdx.x * BN;
    const int l8r = lane >> 3, l8c = lane & 7;
    const int gch = ((l8c ^ l8r) * 8);

    floatx4 acc[MT][NT] = {};

    for (int k0 = 0; k0 < K; k0 += 64) {
        __syncthreads();
#pragma unroll
        for (int c = 0; c < BM / 32; ++c) {
            int r = wave * (BM / 4) + c * 8;
            async16(A + (size_t)(m0 + r + l8r) * K + k0 + gch, &As[r * 64]);
        }
#pragma unroll
        for (int c = 0; c < BN / 32; ++c) {
            int r = wave * (BN / 4) + c * 8;
            async16(Bt + (size_t)(n0 + r + l8r) * K + k0 + gch, &Bs[r * 64]);
        }
        __syncthreads();
#pragma unroll
        for (int cc = 0; cc < 2; ++cc) {
            bf16x8 af[MT], bv[NT];
#pragma unroll
            for (int i = 0; i < MT; ++i) {
                int row = wm * (BM / 2) + i * 16 + l16;
                af[i] = *(const bf16x8*)&As[row * 64 + ((cc * 4 + quad) ^ (row & 7)) * 8];
            }
#pragma unroll
            for (int j = 0; j < NT; ++j) {
                int row = wn * (BN / 2) + j * 16 + l16;
                bv[j] = *(const bf16x8*)&Bs[row * 64 + ((cc * 4 + quad) ^ (row & 7)) * 8];
            }
#pragma unroll
            for (int i = 0; i < MT; ++i)
#pragma unroll
                for (int j = 0; j < NT; ++j)
                    acc[i][j] = MFMA16(af[i], bv[j], acc[i][j]);
        }
    }

#pragma unroll
    for (int i = 0; i < MT; ++i)
#pragma unroll
        for (int j = 0; j < NT; ++j)
#pragma unroll
            for (int r = 0; r < 4; ++r) {
                int row = m0 + wm * (BM / 2) + i * 16 + quad * 4 + r;
                int col = n0 + wn * (BN / 2) + j * 16 + l16;
                if (OUT_BF16)
                    ((bf16*)C)[(size_t)row * ldc + col] = (bf16)acc[i][j][r];
                else
                    ((float*)C)[(size_t)row * ldc + col] = acc[i][j][r] + bias[col];
            }
}

// ---------------- fused causal attention, S^T formulation ----------------
// Flat grid 512; XCD-aware decode: xcd = g&7 owns bh in [xcd*4, xcd*4+4).
// Block handles q-tiles qp and 31-qp (constant 33 k-iterations).
// S^T = K @ Q^T: each lane owns one q-column (l16) and 16 keys -> reductions
// are in-lane + 2 shuffles. Running denominator via MFMA ones-column (acc5).
// K/V LDS double-buffered -> 1 barrier/iter.
__global__ __launch_bounds__(256) void attn_kernel(const bf16* __restrict__ QKV,
                                                   const bf16* __restrict__ Vt_g,
                                                   bf16* __restrict__ ctx) {
    __shared__ bf16 Qs[64][72];
    __shared__ bf16 Ks[2][64][72];
    __shared__ bf16 Vt[2][64][72];   // [hd][key]
    __shared__ bf16 Ps[4][16][72];   // per-wave P tile [q_local][key]

    const int tid = threadIdx.x, wave = tid >> 6, lane = tid & 63;
    const int quad = lane >> 4, l16 = lane & 15;
    const int g = blockIdx.x;
    const int xcd = g & 7, rr = g >> 3;
    const int bh = xcd * 4 + (rr & 3), qp = rr >> 2;
    const int b = bh >> 4, h = bh & 15;
    const int srow = tid >> 2, sseg = tid & 3;
    const size_t base = (size_t)(b * SS) * N_QKV;
    const bf16* Vg = Vt_g + (size_t)bh * 64 * SS;
    constexpr float C2 = 0.18033688011112042f;  // 0.125 * log2(e)

    // ones B-frag for the denominator column (n==0 only)
    bf16x8 onesf = {};
    if (l16 == 0) {
#pragma unroll
        for (int e = 0; e < 8; ++e) onesf[e] = (bf16)1.0f;
    }

    for (int half = 0; half < 2; ++half) {
        const int qt = half ? (31 - qp) : qp;
        const int q0 = qt * 64;

        {   // stage Q tile (safe: all Q reads are pre-loop reg hoists)
            const uint4* pq = (const uint4*)(QKV + base + (size_t)(q0 + srow) * N_QKV
                                             + h * 64 + sseg * 16);
            uint4 a = pq[0], bq = pq[1];
            uint4* d = (uint4*)&Qs[srow][sseg * 16];
            d[0] = a; d[1] = bq;
        }
        // prefetch kv tile 0 into registers
        uint4 kr0, kr1, vr0, vr1;
        {
            const uint4* pk = (const uint4*)(QKV + base + (size_t)srow * N_QKV
                                             + DD + h * 64 + sseg * 16);
            kr0 = pk[0]; kr1 = pk[1];
            const uint4* pv = (const uint4*)(Vg + (size_t)srow * SS + sseg * 16);
            vr0 = pv[0]; vr1 = pv[1];
        }
        __syncthreads();   // Qs staged by all waves; prior half fully done

        // hoisted Q B-frags (this wave's 16 q's)
        const bf16x8 qf0 = *(const bf16x8*)&Qs[wave * 16 + l16][quad * 8];
        const bf16x8 qf1 = *(const bf16x8*)&Qs[wave * 16 + l16][32 + quad * 8];
        const int qg = q0 + wave * 16 + l16;   // this lane's global q

        floatx4 accv[4] = {};
        floatx4 acc5 = {};                      // denominator column
        float m_run = -__builtin_inff();

        for (int kt = 0; kt <= qt; ++kt) {
            const int buf = kt & 1;
            {   // commit prefetched tile
                uint4* dk = (uint4*)&Ks[buf][srow][sseg * 16];
                dk[0] = kr0; dk[1] = kr1;
                uint4* dv = (uint4*)&Vt[buf][srow][sseg * 16];
                dv[0] = vr0; dv[1] = vr1;
            }
            __syncthreads();   // single barrier per iteration (double-buffered)
            if (kt < qt) {
                int k0n = (kt + 1) * 64;
                const uint4* pk = (const uint4*)(QKV + base + (size_t)(k0n + srow) * N_QKV
                                                 + DD + h * 64 + sseg * 16);
                kr0 = pk[0]; kr1 = pk[1];
                const uint4* pv = (const uint4*)(Vg + (size_t)srow * SS + k0n + sseg * 16);
                vr0 = pv[0]; vr1 = pv[1];
            }
            const int k0 = kt * 64;

            // S^T tile: rows = keys, cols = q. st[j] reg r = S[key=k0+j*16+quad*4+r][q=qg]
            floatx4 st[4];
#pragma unroll
            for (int j = 0; j < 4; ++j) {
                bf16x8 kf0 = *(const bf16x8*)&Ks[buf][j * 16 + l16][quad * 8];
                bf16x8 kf1 = *(const bf16x8*)&Ks[buf][j * 16 + l16][32 + quad * 8];
                floatx4 t = {};
                t = MFMA16(kf0, qf0, t);
                t = MFMA16(kf1, qf1, t);
                st[j] = t;
            }

            // causal mask (unscaled; scale folded into exp2)
#pragma unroll
            for (int j = 0; j < 4; ++j) {
                int kb = k0 + j * 16 + quad * 4;
#pragma unroll
                for (int r = 0; r < 4; ++r)
                    if (kb + r > qg) st[j][r] = -__builtin_inff();
            }

            // max over this lane's 16 keys, then across quad replicas (2 shuffles)
            float mloc = fmaxf(fmaxf(st[0][0], st[0][1]), fmaxf(st[0][2], st[0][3]));
#pragma unroll
            for (int j = 1; j < 4; ++j)
                mloc = fmaxf(mloc, fmaxf(fmaxf(st[j][0], st[j][1]),
                                         fmaxf(st[j][2], st[j][3])));
            mloc = fmaxf(mloc, __shfl_xor(mloc, 16, 64));
            mloc = fmaxf(mloc, __shfl_xor(mloc, 32, 64));

            const float m_new = fmaxf(m_run, mloc);
            const float alpha = exp2c((m_run - m_new) * C2);
            const float mm = m_new * C2;
            m_run = m_new;

            // P = exp2(s*C2 - mm), write to Ps[q][key] as packed b64
#pragma unroll
            for (int j = 0; j < 4; ++j) {
                bf16x4 pk;
#pragma unroll
                for (int r = 0; r < 4; ++r) {
                    float p = exp2c(fmaf(st[j][r], C2, -mm));
                    pk[r] = (bf16)p;
                }
                *(bf16x4*)&Ps[wave][l16][j * 16 + quad * 4] = pk;
            }

            // broadcast alpha from softmax layout (per l16) to C layout (per quad*4+r)
            const int bsrc = (lane & 48) | ((lane >> 2) & 12);
            float ar[4];
#pragma unroll
            for (int r = 0; r < 4; ++r) ar[r] = __shfl(alpha, bsrc + r, 64);
#pragma unroll
            for (int j = 0; j < 4; ++j)
#pragma unroll
                for (int r = 0; r < 4; ++r) accv[j][r] *= ar[r];
#pragma unroll
            for (int r = 0; r < 4; ++r) acc5[r] *= ar[r];

            // ctx += P(16x64) @ V ; denominator column via ones-frag
            bf16x8 pf0 = *(const bf16x8*)&Ps[wave][l16][quad * 8];
            bf16x8 pf1 = *(const bf16x8*)&Ps[wave][l16][32 + quad * 8];
#pragma unroll
            for (int j = 0; j < 4; ++j) {
                bf16x8 vt0 = *(const bf16x8*)&Vt[buf][j * 16 + l16][quad * 8];
                bf16x8 vt1 = *(const bf16x8*)&Vt[buf][j * 16 + l16][32 + quad * 8];
                accv[j] = MFMA16(pf0, vt0, accv[j]);
                accv[j] = MFMA16(pf1, vt1, accv[j]);
            }
            acc5 = MFMA16(pf0, onesf, acc5);
            acc5 = MFMA16(pf1, onesf, acc5);
        }

        // epilogue: l lives in acc5 at lanes l16==0 (reg r = row quad*4+r)
        float inv[4];
#pragma unroll
        for (int r = 0; r < 4; ++r) {
            float lr = __shfl(acc5[r], lane & 48, 64);
            inv[r] = 1.0f / lr;
        }
#pragma unroll
        for (int j = 0; j < 4; ++j)
#pragma unroll
            for (int r = 0; r < 4; ++r) {
                int row = b * SS + q0 + wave * 16 + quad * 4 + r;
                int col = h * 64 + j * 16 + l16;
                ctx[(size_t)row * DD + col] = (bf16)(accv[j][r] * inv[r]);
            }
    }
}

extern "C" void kernel_launch(void* const* d_in, const int* in_sizes, int n_in,
                              void* d_out, int out_size, void* d_ws, size_t ws_size,
                              hipStream_t stream) {
    const float* x  = (const float*)d_in[0];
    const float* Wq = (const float*)d_in[1];
    const float* Wk = (const float*)d_in[2];
    const float* Wv = (const float*)d_in[3];
    const float* Wo = (const float*)d_in[4];
    const float* bo = (const float*)d_in[5];
    float* out = (float*)d_out;

    char* ws = (char*)d_ws;
    bf16* xb   = (bf16*)ws;                         //  8 MB
    bf16* WT   = (bf16*)(ws + (size_t)(8  << 20));  //  8 MB
    bf16* QKV  = (bf16*)(ws + (size_t)(16 << 20));  // 24 MB
    bf16* ctxb = (bf16*)(ws + (size_t)(40 << 20));  //  8 MB
    bf16* Vt_g = (bf16*)(ws + (size_t)(48 << 20));  //  8 MB

    cvt_x_kernel<<<dim3(MM * DD / (256 * 4)), dim3(256), 0, stream>>>(x, xb);
    cvt_wT_kernel<<<dim3(32, 32, 4), dim3(32, 8), 0, stream>>>(Wq, Wk, Wv, Wo, WT);
    gemm_kernel<128, 128, true><<<dim3(N_QKV / 128, MM / 128), dim3(256), 0, stream>>>(
        xb, WT, QKV, nullptr, DD, N_QKV);
    transpose_v_kernel<<<dim3(SS / 64, BB * HH), dim3(256), 0, stream>>>(QKV, Vt_g);
    attn_kernel<<<dim3(512), dim3(256), 0, stream>>>(QKV, Vt_g, ctxb);
    gemm_kernel<128, 64, false><<<dim3(DD / 64, MM / 128), dim3(256), 0, stream>>>(
        ctxb, WT + (size_t)3 * DD * DD, out, bo, DD, DD);
}